// Round 1
// baseline (34929.926 us; speedup 1.0000x reference)
//
#include <hip/hip_runtime.h>
#include <cstdint>
#include <cstddef>

#define DEVINL __device__ __forceinline__

namespace {
constexpr int kB   = 64;     // batch
constexpr int kH   = 1024;   // hidden
constexpr int kE   = 1024;   // embed dim
constexpr int kG4  = 4096;   // 4*H
constexpr int kV   = 32000;  // vocab
constexpr int NBLK = 512;
constexpr int NTHR = 256;
constexpr int START_INDEX = 1;
}

struct WsPtrs {
  float* G0;              // [64][4096] gate accum layer0 (f32, atomic)
  float* G1;              // [64][4096] layer1
  float* h0s;             // [64][1024]
  float* h1s;             // [64][1024]
  float* c0s;             // [2][64][1024] parity double-buffer
  float* c1s;             // [64][1024]
  unsigned long long* keys; // [T][64] packed argmax keys
  unsigned* bar;          // bar[0]=cnt, bar[16]=gen
};

DEVINL double sigd(double x) { return 1.0 / (1.0 + exp(-x)); }

DEVINL unsigned long long packKey(float v, unsigned idx) {
  unsigned u = __float_as_uint(v);
  u = (u & 0x80000000u) ? ~u : (u | 0x80000000u);
  // larger value wins; equal value -> smaller index wins (first occurrence)
  return ((unsigned long long)u << 32) | (0xFFFFFFFFu - idx);
}

DEVINL void gbar(unsigned* bar) {
  __syncthreads();
  if (threadIdx.x == 0) {
    __threadfence();
    unsigned* cnt = bar;
    unsigned* gen = bar + 16;
    unsigned g = __hip_atomic_load(gen, __ATOMIC_RELAXED, __HIP_MEMORY_SCOPE_AGENT);
    unsigned prev = __hip_atomic_fetch_add(cnt, 1u, __ATOMIC_ACQ_REL, __HIP_MEMORY_SCOPE_AGENT);
    if (prev == (unsigned)(NBLK - 1)) {
      __hip_atomic_store(cnt, 0u, __ATOMIC_RELAXED, __HIP_MEMORY_SCOPE_AGENT);
      __hip_atomic_store(gen, g + 1u, __ATOMIC_RELEASE, __HIP_MEMORY_SCOPE_AGENT);
    } else {
      while (__hip_atomic_load(gen, __ATOMIC_RELAXED, __HIP_MEMORY_SCOPE_AGENT) == g) {
        __builtin_amdgcn_s_sleep(2);
      }
    }
    __threadfence();
  }
  __syncthreads();
}

DEVINL void lstm_elem(double gi, double gf, double gg, double go, double c,
                      double* cn, double* hn) {
  double cc = sigd(gf) * c + sigd(gi) * tanh(gg);
  *cn = cc;
  *hn = sigd(go) * tanh(cc);
}

// GEMM for gate phases: C[64b x 128n] over K-chunk of 128, from sX [64][132]
// (natural [b][k]) and W staged transposed+swizzled per 32-k slice.
// Accumulate fp32 with fp64 spill per 32 terms; atomicAdd f32 into Gdst.
DEVINL void gates_gemm_accum(const float* __restrict__ Wsrc, int kwb, int n0,
                             float* __restrict__ Gdst,
                             float* sX, float* sW, int tid)
{
  const int tx = tid & 15, ty = tid >> 4;
  float acc[4][8];
  double accd[4][8];
  #pragma unroll
  for (int i = 0; i < 4; ++i)
    #pragma unroll
    for (int j = 0; j < 8; ++j) { acc[i][j] = 0.f; accd[i][j] = 0.0; }

  for (int kt = 0; kt < 4; ++kt) {
    // stage W slice: 128 rows (n) x 32 cols (k), transposed into sW[k*128 + (n^swz)]
    #pragma unroll
    for (int r = 0; r < 4; ++r) {
      int idx = r * NTHR + tid;
      int n = idx >> 3, q = idx & 7;
      const float* src = Wsrc + (size_t)(n0 + n) * kH + kwb + kt * 32 + q * 4;
      float4 v = *(const float4*)src;
      int row = q * 4;
      int col = n ^ (row & 28);
      sW[(row + 0) * 128 + col] = v.x;
      sW[(row + 1) * 128 + col] = v.y;
      sW[(row + 2) * 128 + col] = v.z;
      sW[(row + 3) * 128 + col] = v.w;
    }
    __syncthreads();
    #pragma unroll 8
    for (int k = 0; k < 32; ++k) {
      int kk = kt * 32 + k;
      float xsv[4];
      #pragma unroll
      for (int bb = 0; bb < 4; ++bb) xsv[bb] = sX[(ty * 4 + bb) * 132 + kk];
      int swz = k & 28;
      float4 w0 = *(const float4*)&sW[k * 128 + ((tx * 8) ^ swz)];
      float4 w1 = *(const float4*)&sW[k * 128 + (((tx * 8) + 4) ^ swz)];
      float wv[8] = {w0.x, w0.y, w0.z, w0.w, w1.x, w1.y, w1.z, w1.w};
      #pragma unroll
      for (int bb = 0; bb < 4; ++bb)
        #pragma unroll
        for (int nn = 0; nn < 8; ++nn)
          acc[bb][nn] = fmaf(xsv[bb], wv[nn], acc[bb][nn]);
    }
    __syncthreads();
    #pragma unroll
    for (int bb = 0; bb < 4; ++bb)
      #pragma unroll
      for (int nn = 0; nn < 8; ++nn) { accd[bb][nn] += (double)acc[bb][nn]; acc[bb][nn] = 0.f; }
  }
  #pragma unroll
  for (int bb = 0; bb < 4; ++bb) {
    int b = ty * 4 + bb;
    #pragma unroll
    for (int nn = 0; nn < 8; ++nn)
      atomicAdd(&Gdst[(size_t)b * kG4 + n0 + tx * 8 + nn], (float)accd[bb][nn]);
  }
}

__global__ __launch_bounds__(NTHR, 2) void stack_lstm_persistent(
    const float* __restrict__ hidden, const float* __restrict__ emb,
    const float* __restrict__ Wih0, const float* __restrict__ Whh0,
    const float* __restrict__ bih0, const float* __restrict__ bhh0,
    const float* __restrict__ Wih1, const float* __restrict__ Whh1,
    const float* __restrict__ bih1, const float* __restrict__ bhh1,
    const float* __restrict__ Wout, const float* __restrict__ bout,
    float* __restrict__ out, int T, WsPtrs ws)
{
  __shared__ float sX[64 * 132];   // 33,792 B
  __shared__ float sW[32 * 128];   // 16,384 B (also serves D's 64x64)
  __shared__ int last_l[kB];

  const int tid = threadIdx.x;
  const int bid = blockIdx.x;

  // ---------------- init ----------------
  {
    int gt = bid * NTHR + tid;
    for (int i = gt; i < kB * kG4; i += NBLK * NTHR) { ws.G0[i] = 0.f; ws.G1[i] = 0.f; }
    for (int i = gt; i < kB * kH; i += NBLK * NTHR) {
      ws.h0s[i] = hidden[i];
      ws.h1s[i] = hidden[kB * kH + i];
      ws.c0s[i] = 0.f;
      ws.c0s[kB * kH + i] = 0.f;
      ws.c1s[i] = 0.f;
    }
    for (int i = gt; i < T * kB; i += NBLK * NTHR) ws.keys[i] = 0ull;
  }
  gbar(ws.bar);

  #pragma unroll 1
  for (int t = 0; t < T; ++t) {
    const int p = t & 1;

    // ============ PHASE A: layer-0 gates into G0 (+ zero G1) ============
    {
      const int nt = bid >> 4, kc = bid & 15;
      const int n0 = nt * 128, k0 = kc * 128;
      const bool xpart = (kc < 8);
      if (tid < kB) {
        int tok = START_INDEX;
        if (t > 0)
          tok = (int)(0xFFFFFFFFu -
                      (unsigned)(ws.keys[(size_t)(t - 1) * kB + tid] & 0xFFFFFFFFull));
        last_l[tid] = tok;
      }
      __syncthreads();
      #pragma unroll
      for (int r = 0; r < 8; ++r) {
        int idx = r * NTHR + tid;
        int b = idx >> 5, q = idx & 31;
        float4 v;
        if (xpart) v = *(const float4*)(emb + (size_t)last_l[b] * kE + k0 + q * 4);
        else       v = *(const float4*)(ws.h0s + (size_t)b * kH + (k0 - kE) + q * 4);
        *(float4*)&sX[b * 132 + q * 4] = v;
      }
      gates_gemm_accum(xpart ? Wih0 : Whh0, xpart ? k0 : (k0 - kE), n0, ws.G0, sX, sW, tid);
      #pragma unroll
      for (int r = 0; r < 2; ++r) ws.G1[(size_t)bid * 512 + r * NTHR + tid] = 0.f;
    }
    gbar(ws.bar);

    // ============ PHASE B: layer-1 gates into G1 (inline elem0 for X) ============
    {
      const int nt = bid >> 4, kc = bid & 15;
      const int n0 = nt * 128, k0 = kc * 128;
      const bool xpart = (kc < 8);
      if (xpart) {
        const float* c0rd = ws.c0s + (size_t)p * kB * kH;
        float* c0wr = ws.c0s + (size_t)(p ^ 1) * kB * kH;
        #pragma unroll 4
        for (int r = 0; r < 32; ++r) {
          int idx = r * NTHR + tid;
          int b = idx >> 7, ul = idx & 127;
          int u = k0 + ul;
          size_t gb = (size_t)b * kG4;
          double gi = (double)ws.G0[gb + u]          + (double)bih0[u]          + (double)bhh0[u];
          double gf = (double)ws.G0[gb + kH + u]     + (double)bih0[kH + u]     + (double)bhh0[kH + u];
          double gg = (double)ws.G0[gb + 2*kH + u]   + (double)bih0[2*kH + u]   + (double)bhh0[2*kH + u];
          double go = (double)ws.G0[gb + 3*kH + u]   + (double)bih0[3*kH + u]   + (double)bhh0[3*kH + u];
          double c = (double)c0rd[b * kH + u];
          double cn, hn;
          lstm_elem(gi, gf, gg, go, c, &cn, &hn);
          sX[b * 132 + ul] = (float)hn;
          if (nt == 0) { ws.h0s[b * kH + u] = (float)hn; c0wr[b * kH + u] = (float)cn; }
        }
      } else {
        #pragma unroll
        for (int r = 0; r < 8; ++r) {
          int idx = r * NTHR + tid;
          int b = idx >> 5, q = idx & 31;
          float4 v = *(const float4*)(ws.h1s + (size_t)b * kH + (k0 - kE) + q * 4);
          *(float4*)&sX[b * 132 + q * 4] = v;
        }
      }
      gates_gemm_accum(xpart ? Wih1 : Whh1, xpart ? k0 : (k0 - kE), n0, ws.G1, sX, sW, tid);
    }
    gbar(ws.bar);

    // ============ PHASE C: elem1 -> h1s/c1s ; zero G0 ============
    {
      if (bid < 128) {
        #pragma unroll
        for (int r = 0; r < 2; ++r) {
          int unit = bid * 512 + r * NTHR + tid;
          int b = unit >> 10, u = unit & 1023;
          size_t gb = (size_t)b * kG4;
          double gi = (double)ws.G1[gb + u]          + (double)bih1[u]          + (double)bhh1[u];
          double gf = (double)ws.G1[gb + kH + u]     + (double)bih1[kH + u]     + (double)bhh1[kH + u];
          double gg = (double)ws.G1[gb + 2*kH + u]   + (double)bih1[2*kH + u]   + (double)bhh1[2*kH + u];
          double go = (double)ws.G1[gb + 3*kH + u]   + (double)bih1[3*kH + u]   + (double)bhh1[3*kH + u];
          double c = (double)ws.c1s[b * kH + u];
          double cn, hn;
          lstm_elem(gi, gf, gg, go, c, &cn, &hn);
          ws.h1s[b * kH + u] = (float)hn;
          ws.c1s[b * kH + u] = (float)cn;
        }
      } else if (bid < 384) {
        float* z = ws.G0 + (size_t)(bid - 128) * 1024;
        #pragma unroll
        for (int r = 0; r < 4; ++r) z[r * NTHR + tid] = 0.f;
      }
    }
    gbar(ws.bar);

    // ============ PHASE D: logits = h1' @ Wout^T + bout ; write out ; argmax ============
    if (bid < 500) {
      const int v0 = bid * 64;
      const int tx = tid & 15, ty = tid >> 4;
      float acc[4][4];
      double accd[4][4];
      #pragma unroll
      for (int i = 0; i < 4; ++i)
        #pragma unroll
        for (int j = 0; j < 4; ++j) { acc[i][j] = 0.f; accd[i][j] = 0.0; }

      for (int ks = 0; ks < 16; ++ks) {
        const int k0 = ks * 64;
        #pragma unroll
        for (int r = 0; r < 4; ++r) {
          int idx = r * NTHR + tid;
          int b = idx >> 4, q = idx & 15;
          float4 v = *(const float4*)(ws.h1s + (size_t)b * kH + k0 + q * 4);
          *(float4*)&sX[b * 68 + q * 4] = v;
        }
        #pragma unroll
        for (int r = 0; r < 4; ++r) {
          int idx = r * NTHR + tid;
          int vr = idx >> 4, q = idx & 15;
          float4 w = *(const float4*)(Wout + (size_t)(v0 + vr) * kH + k0 + q * 4);
          int row = q * 4;
          int col = vr ^ (row & 60);
          sW[(row + 0) * 64 + col] = w.x;
          sW[(row + 1) * 64 + col] = w.y;
          sW[(row + 2) * 64 + col] = w.z;
          sW[(row + 3) * 64 + col] = w.w;
        }
        __syncthreads();
        #pragma unroll 8
        for (int k = 0; k < 64; ++k) {
          float xs[4];
          #pragma unroll
          for (int bb = 0; bb < 4; ++bb) xs[bb] = sX[(ty * 4 + bb) * 68 + k];
          float4 wq = *(const float4*)&sW[k * 64 + ((tx * 4) ^ (k & 60))];
          float wvv[4] = {wq.x, wq.y, wq.z, wq.w};
          #pragma unroll
          for (int bb = 0; bb < 4; ++bb)
            #pragma unroll
            for (int j = 0; j < 4; ++j)
              acc[bb][j] = fmaf(xs[bb], wvv[j], acc[bb][j]);
          if ((k & 31) == 31) {
            #pragma unroll
            for (int bb = 0; bb < 4; ++bb)
              #pragma unroll
              for (int j = 0; j < 4; ++j) { accd[bb][j] += (double)acc[bb][j]; acc[bb][j] = 0.f; }
          }
        }
        __syncthreads();
      }
      // epilogue: bias, store, argmax
      float bo[4];
      #pragma unroll
      for (int j = 0; j < 4; ++j) bo[j] = bout[v0 + tx * 4 + j];
      #pragma unroll
      for (int bb = 0; bb < 4; ++bb) {
        int b = ty * 4 + bb;
        float4 o;
        o.x = (float)(accd[bb][0] + (double)bo[0]);
        o.y = (float)(accd[bb][1] + (double)bo[1]);
        o.z = (float)(accd[bb][2] + (double)bo[2]);
        o.w = (float)(accd[bb][3] + (double)bo[3]);
        *(float4*)(out + ((size_t)b * T + t) * (size_t)kV + v0 + tx * 4) = o;
        unsigned vb = (unsigned)(v0 + tx * 4);
        unsigned long long key = packKey(o.x, vb);
        unsigned long long k2 = packKey(o.y, vb + 1); if (k2 > key) key = k2;
        k2 = packKey(o.z, vb + 2); if (k2 > key) key = k2;
        k2 = packKey(o.w, vb + 3); if (k2 > key) key = k2;
        #pragma unroll
        for (int m = 1; m < 16; m <<= 1) {
          unsigned long long ok = __shfl_xor(key, m, 16);
          if (ok > key) key = ok;
        }
        if (tx == 0) atomicMax(&ws.keys[(size_t)t * kB + b], key);
        // reset per-row acc for next t
        #pragma unroll
        for (int j = 0; j < 4; ++j) { acc[bb][j] = 0.f; accd[bb][j] = 0.0; }
      }
    }
    gbar(ws.bar);
  }
}

extern "C" void kernel_launch(void* const* d_in, const int* in_sizes, int n_in,
                              void* d_out, int out_size, void* d_ws, size_t ws_size,
                              hipStream_t stream) {
  (void)in_sizes; (void)n_in; (void)ws_size;
  const float* hidden = (const float*)d_in[0];
  const float* emb    = (const float*)d_in[1];
  const float* Wih0   = (const float*)d_in[2];
  const float* Whh0   = (const float*)d_in[3];
  const float* bih0   = (const float*)d_in[4];
  const float* bhh0   = (const float*)d_in[5];
  const float* Wih1   = (const float*)d_in[6];
  const float* Whh1   = (const float*)d_in[7];
  const float* bih1   = (const float*)d_in[8];
  const float* bhh1   = (const float*)d_in[9];
  const float* Wout   = (const float*)d_in[10];
  const float* bout   = (const float*)d_in[11];
  float* out = (float*)d_out;

  const int T = out_size / (kB * kV);
  if (T <= 0) return;

  char* w = (char*)d_ws;
  WsPtrs ws;
  ws.G0  = (float*)w; w += (size_t)kB * kG4 * 4;
  ws.G1  = (float*)w; w += (size_t)kB * kG4 * 4;
  ws.h0s = (float*)w; w += (size_t)kB * kH * 4;
  ws.h1s = (float*)w; w += (size_t)kB * kH * 4;
  ws.c0s = (float*)w; w += (size_t)2 * kB * kH * 4;
  ws.c1s = (float*)w; w += (size_t)kB * kH * 4;
  ws.keys = (unsigned long long*)w; w += (size_t)T * kB * 8;
  uintptr_t a = ((uintptr_t)w + 127) & ~(uintptr_t)127;
  ws.bar = (unsigned*)a;

  hipMemsetAsync((void*)ws.bar, 0, 256, stream);
  hipLaunchKernelGGL(stack_lstm_persistent, dim3(NBLK), dim3(NTHR), 0, stream,
                     hidden, emb, Wih0, Whh0, bih0, bhh0,
                     Wih1, Whh1, bih1, bhh1, Wout, bout,
                     out, T, ws);
}

// Round 2
// 18223.743 us; speedup vs baseline: 1.9167x; 1.9167x over previous
//
#include <hip/hip_runtime.h>
#include <cstdint>
#include <cstddef>

#define DEVINL __device__ __forceinline__

typedef unsigned short ushort_t;
typedef unsigned long long u64;
typedef __attribute__((ext_vector_type(8))) short bf16x8;
typedef __attribute__((ext_vector_type(4))) float f32x4;

namespace {
constexpr int kB = 64, kH = 1024, kG4 = 4096, kV = 32000;
constexpr int NBLK = 512, NTHR = 256;
constexpr int NKC = 16;      // K-split chunks for gate GEMMs (2048/128)
constexpr int EBLK = 250;    // logits blocks: 250 x 128 vocab cols
constexpr int START_INDEX = 1;
constexpr float GAP_THR = 1e-3f;
}

struct WsPtrs {
  float* P;                        // [16][64][4096] gate partials (f32, exact per-partial)
  float* c0s; float* c1s;          // [64][1024] cell states
  float* h1s;                      // [64][1024] fp32 h1 (for exact rescue)
  ushort_t *h0hi, *h0lo;           // [64][1024] bf16 hi/lo decomposition
  ushort_t *h1hi, *h1lo;
  u64 *btop1, *btop2;              // [64][256] per-logits-block top-2 keys
  int* lastArr;                    // [T][64] chosen tokens
  unsigned* bar;                   // barrier: [0]=gen, [16]=root, [32+g*16]=group g
};

// ---------- numeric helpers ----------
DEVINL ushort_t bf16rne(float f) {
  unsigned u = __float_as_uint(f);
  unsigned r = (u + 0x7FFFu + ((u >> 16) & 1u)) >> 16;
  return (ushort_t)r;
}
DEVINL float bf2f(ushort_t h) { return __uint_as_float(((unsigned)h) << 16); }

DEVINL u64 packKey(float v, unsigned idx) {
  unsigned u = __float_as_uint(v);
  u = (u & 0x80000000u) ? ~u : (u | 0x80000000u);
  return ((u64)u << 32) | (0xFFFFFFFFu - idx);   // bigger val wins; tie -> smaller idx
}
DEVINL float keyVal(u64 k) {
  unsigned u = (unsigned)(k >> 32);
  u = (u & 0x80000000u) ? (u & 0x7FFFFFFFu) : ~u;
  return __uint_as_float(u);
}
DEVINL int keyIdx(u64 k) { return (int)(0xFFFFFFFFu - (unsigned)(k & 0xFFFFFFFFull)); }

DEVINL void mergeTop2(u64& a1, u64& a2, u64 b1, u64 b2) {
  u64 n1 = a1 > b1 ? a1 : b1;
  u64 mn = a1 > b1 ? b1 : a1;
  u64 mx2 = a2 > b2 ? a2 : b2;
  a1 = n1;
  a2 = mn > mx2 ? mn : mx2;
}

// ---------- grid barrier (2-level, sense via generation counter) ----------
DEVINL void gbar(unsigned* bar, int bid) {
  __syncthreads();
  if (threadIdx.x == 0) {
    __threadfence();
    unsigned g = __hip_atomic_load(bar, __ATOMIC_RELAXED, __HIP_MEMORY_SCOPE_AGENT);
    unsigned* grp = bar + 32 + ((bid >> 4) << 4);
    if (__hip_atomic_fetch_add(grp, 1u, __ATOMIC_ACQ_REL, __HIP_MEMORY_SCOPE_AGENT) == 15u) {
      __hip_atomic_store(grp, 0u, __ATOMIC_RELAXED, __HIP_MEMORY_SCOPE_AGENT);
      if (__hip_atomic_fetch_add(bar + 16, 1u, __ATOMIC_ACQ_REL, __HIP_MEMORY_SCOPE_AGENT) == 31u) {
        __hip_atomic_store(bar + 16, 0u, __ATOMIC_RELAXED, __HIP_MEMORY_SCOPE_AGENT);
        __hip_atomic_store(bar, g + 1u, __ATOMIC_RELEASE, __HIP_MEMORY_SCOPE_AGENT);
      }
    }
    while (__hip_atomic_load(bar, __ATOMIC_RELAXED, __HIP_MEMORY_SCOPE_AGENT) == g) {
      __builtin_amdgcn_s_sleep(2);
    }
    __threadfence();
  }
  __syncthreads();
}

// ---------- LDS staging (swizzled: 16B-block index XORed with row&7) ----------
DEVINL void stage_copy8(const ushort_t* ghi, const ushort_t* glo,
                        ushort_t* shi, ushort_t* slo, int row, int k8) {
  uint4 vh = *(const uint4*)ghi;
  uint4 vl = *(const uint4*)glo;
  int di = row * 64 + (((k8 >> 3) ^ (row & 7)) << 3);
  *(uint4*)(shi + di) = vh;
  *(uint4*)(slo + di) = vl;
}
DEVINL void stage_cvt8(const float* src, ushort_t* shi, ushort_t* slo, int row, int k8) {
  float4 f0 = *(const float4*)(src);
  float4 f1 = *(const float4*)(src + 4);
  float ff[8] = {f0.x, f0.y, f0.z, f0.w, f1.x, f1.y, f1.z, f1.w};
  unsigned hh[8], ll[8];
  #pragma unroll
  for (int j = 0; j < 8; ++j) {
    ushort_t h = bf16rne(ff[j]);
    hh[j] = h;
    ll[j] = bf16rne(ff[j] - bf2f(h));
  }
  uint4 vh, vl;
  vh.x = hh[0] | (hh[1] << 16); vh.y = hh[2] | (hh[3] << 16);
  vh.z = hh[4] | (hh[5] << 16); vh.w = hh[6] | (hh[7] << 16);
  vl.x = ll[0] | (ll[1] << 16); vl.y = ll[2] | (ll[3] << 16);
  vl.z = ll[4] | (ll[5] << 16); vl.w = ll[6] | (ll[7] << 16);
  int di = row * 64 + (((k8 >> 3) ^ (row & 7)) << 3);
  *(uint4*)(shi + di) = vh;
  *(uint4*)(slo + di) = vl;
}

// ---------- MFMA over one 64-k LDS chunk: wave tile [64b x 32n], bf16x3 ----------
DEVINL void mma64(const ushort_t* sXhi, const ushort_t* sXlo,
                  const ushort_t* sWhi, const ushort_t* sWlo,
                  int wv, int lane, f32x4 acc[4][2]) {
  const int l15 = lane & 15, l4 = lane >> 4;
  #pragma unroll
  for (int ks = 0; ks < 2; ++ks) {
    const int kk = ks * 32 + l4 * 8;
    bf16x8 ah[4], al[4];
    #pragma unroll
    for (int mt = 0; mt < 4; ++mt) {
      int r = mt * 16 + l15;
      int di = r * 64 + (((kk >> 3) ^ (r & 7)) << 3);
      ah[mt] = *(const bf16x8*)(sXhi + di);
      al[mt] = *(const bf16x8*)(sXlo + di);
    }
    #pragma unroll
    for (int ntl = 0; ntl < 2; ++ntl) {
      int r = wv * 32 + ntl * 16 + l15;
      int di = r * 64 + (((kk >> 3) ^ (r & 7)) << 3);
      bf16x8 bh = *(const bf16x8*)(sWhi + di);
      bf16x8 bl = *(const bf16x8*)(sWlo + di);
      #pragma unroll
      for (int mt = 0; mt < 4; ++mt) {
        acc[mt][ntl] = __builtin_amdgcn_mfma_f32_16x16x32_bf16(ah[mt], bh, acc[mt][ntl], 0, 0, 0);
        acc[mt][ntl] = __builtin_amdgcn_mfma_f32_16x16x32_bf16(al[mt], bh, acc[mt][ntl], 0, 0, 0);
        acc[mt][ntl] = __builtin_amdgcn_mfma_f32_16x16x32_bf16(ah[mt], bl, acc[mt][ntl], 0, 0, 0);
      }
    }
  }
}

// ---------- gate GEMM phase: block (kc,nt) computes partial [64 x 128n] over 128k ----------
DEVINL void gates_phase(int bid, int tid,
                        const float* Wx, const float* Wh,          // [4096][1024]
                        const ushort_t* xaHi, const ushort_t* xaLo, // k<1024 src (null => emb)
                        const float* emb, const int* last_l,
                        const ushort_t* xbHi, const ushort_t* xbLo, // k>=1024 src
                        float* P,
                        ushort_t* sXhi, ushort_t* sXlo, ushort_t* sWhi, ushort_t* sWlo) {
  const int kc = bid >> 5, nt = bid & 31;
  const int wv = tid >> 6, lane = tid & 63;
  const bool lowk = (kc < 8);
  f32x4 acc[4][2];
  #pragma unroll
  for (int mt = 0; mt < 4; ++mt)
    #pragma unroll
    for (int ntl = 0; ntl < 2; ++ntl) acc[mt][ntl] = (f32x4){0.f, 0.f, 0.f, 0.f};

  #pragma unroll 1
  for (int ch = 0; ch < 2; ++ch) {
    const int kg = kc * 128 + ch * 64;
    __syncthreads();
    // stage X: 64 rows x 64 k  (512 16B-units, 2/thread)
    #pragma unroll
    for (int i = 0; i < 2; ++i) {
      int u = tid * 2 + i;
      int row = u >> 3, g8 = (u & 7) * 8;
      if (lowk) {
        if (emb) {
          stage_cvt8(emb + (size_t)last_l[row] * kH + kg + g8, sXhi, sXlo, row, g8);
        } else {
          size_t go = (size_t)row * kH + kg + g8;
          stage_copy8(xaHi + go, xaLo + go, sXhi, sXlo, row, g8);
        }
      } else {
        size_t go = (size_t)row * kH + (kg - kH) + g8;
        stage_copy8(xbHi + go, xbLo + go, sXhi, sXlo, row, g8);
      }
    }
    // stage W: 128 rows x 64 k (1024 units, 4/thread), convert fp32 -> hi/lo
    const float* Wsel = lowk ? Wx : Wh;
    const int kw = lowk ? kg : kg - kH;
    #pragma unroll
    for (int i = 0; i < 4; ++i) {
      int u = tid * 4 + i;
      int row = u >> 3, g8 = (u & 7) * 8;
      stage_cvt8(Wsel + (size_t)(nt * 128 + row) * kH + kw + g8, sWhi, sWlo, row, g8);
    }
    __syncthreads();
    mma64(sXhi, sXlo, sWhi, sWlo, wv, lane, acc);
  }
  // store partials
  const int l15 = lane & 15, l4 = lane >> 4;
  #pragma unroll
  for (int mt = 0; mt < 4; ++mt)
    #pragma unroll
    for (int ntl = 0; ntl < 2; ++ntl) {
      int n = nt * 128 + wv * 32 + ntl * 16 + l15;
      #pragma unroll
      for (int r = 0; r < 4; ++r) {
        int b = mt * 16 + l4 * 4 + r;
        P[((size_t)kc * kB + b) * kG4 + n] = acc[mt][ntl][r];
      }
    }
}

// ---------- elementwise LSTM cell phase (distributed; deterministic fp64 reduce) ----------
DEVINL void elem_phase(int gt, const float* P, const float* bi, const float* bh,
                       float* cs, ushort_t* hhi, ushort_t* hlo, float* hf32) {
  if (gt >= kB * kH) return;
  int b = gt >> 10, u = gt & 1023;
  double g4[4];
  #pragma unroll
  for (int gi = 0; gi < 4; ++gi) {
    int n = gi * kH + u;
    double s = (double)bi[n] + (double)bh[n];
    #pragma unroll 4
    for (int kc = 0; kc < NKC; ++kc)
      s += (double)P[((size_t)kc * kB + b) * kG4 + n];
    g4[gi] = s;
  }
  double c = (double)cs[gt];
  double ig = 1.0 / (1.0 + exp(-g4[0]));
  double fg = 1.0 / (1.0 + exp(-g4[1]));
  double gg = tanh(g4[2]);
  double og = 1.0 / (1.0 + exp(-g4[3]));
  double cn = fg * c + ig * gg;
  double hn = og * tanh(cn);
  cs[gt] = (float)cn;
  float hf = (float)hn;
  ushort_t h = bf16rne(hf);
  hhi[gt] = h;
  hlo[gt] = bf16rne(hf - bf2f(h));
  if (hf32) hf32[gt] = hf;
}

__global__ __launch_bounds__(NTHR, 2) void stack_lstm_persistent(
    const float* __restrict__ hidden, const float* __restrict__ emb,
    const float* __restrict__ Wih0, const float* __restrict__ Whh0,
    const float* __restrict__ bih0, const float* __restrict__ bhh0,
    const float* __restrict__ Wih1, const float* __restrict__ Whh1,
    const float* __restrict__ bih1, const float* __restrict__ bhh1,
    const float* __restrict__ Wout, const float* __restrict__ bout,
    float* __restrict__ out, int T, WsPtrs ws) {
  __shared__ ushort_t sXhi[64 * 64], sXlo[64 * 64];      // 8KB + 8KB
  __shared__ ushort_t sWhi[128 * 64], sWlo[128 * 64];    // 16KB + 16KB
  __shared__ u64 sRed[512];                              // 4KB (also sD1/sD2 doubles)
  __shared__ int last_l[kB];
  __shared__ u64 sFin[2];

  const int tid = threadIdx.x;
  const int bid = blockIdx.x;
  const int wv = tid >> 6, lane = tid & 63;
  const int l15 = lane & 15, l4 = lane >> 4;

  // ---- init ----
  {
    int gt = bid * NTHR + tid;
    if (gt < kB * kH) {
      float h0f = hidden[gt];
      float h1f = hidden[kB * kH + gt];
      ushort_t a = bf16rne(h0f);
      ws.h0hi[gt] = a; ws.h0lo[gt] = bf16rne(h0f - bf2f(a));
      ushort_t bq = bf16rne(h1f);
      ws.h1hi[gt] = bq; ws.h1lo[gt] = bf16rne(h1f - bf2f(bq));
      ws.h1s[gt] = h1f;
      ws.c0s[gt] = 0.f; ws.c1s[gt] = 0.f;
    }
  }
  gbar(ws.bar, bid);

  #pragma unroll 1
  for (int t = 0; t < T; ++t) {
    // ===== A: layer-0 gates -> P =====
    if (tid < kB) last_l[tid] = (t == 0) ? START_INDEX : ws.lastArr[(t - 1) * kB + tid];
    gates_phase(bid, tid, Wih0, Whh0,
                nullptr, nullptr, emb, last_l,
                ws.h0hi, ws.h0lo, ws.P, sXhi, sXlo, sWhi, sWlo);
    gbar(ws.bar, bid);

    // ===== B: elem0 (reduce P, cell0) -> h0hi/lo, c0s =====
    elem_phase(bid * NTHR + tid, ws.P, bih0, bhh0, ws.c0s, ws.h0hi, ws.h0lo, nullptr);
    gbar(ws.bar, bid);

    // ===== C: layer-1 gates -> P =====
    gates_phase(bid, tid, Wih1, Whh1,
                ws.h0hi, ws.h0lo, nullptr, nullptr,
                ws.h1hi, ws.h1lo, ws.P, sXhi, sXlo, sWhi, sWlo);
    gbar(ws.bar, bid);

    // ===== D: elem1 -> h1hi/lo, h1s, c1s =====
    elem_phase(bid * NTHR + tid, ws.P, bih1, bhh1, ws.c1s, ws.h1hi, ws.h1lo, ws.h1s);
    gbar(ws.bar, bid);

    // ===== E: logits [64 x 128v] per block + per-block top-2 =====
    if (bid < EBLK) {
      const int v0 = bid * 128;
      f32x4 acc[4][2];
      #pragma unroll
      for (int mt = 0; mt < 4; ++mt)
        #pragma unroll
        for (int ntl = 0; ntl < 2; ++ntl) acc[mt][ntl] = (f32x4){0.f, 0.f, 0.f, 0.f};

      #pragma unroll 1
      for (int ch = 0; ch < 16; ++ch) {
        const int k0 = ch * 64;
        __syncthreads();
        #pragma unroll
        for (int i = 0; i < 2; ++i) {
          int u = tid * 2 + i;
          int row = u >> 3, g8 = (u & 7) * 8;
          size_t go = (size_t)row * kH + k0 + g8;
          stage_copy8(ws.h1hi + go, ws.h1lo + go, sXhi, sXlo, row, g8);
        }
        #pragma unroll
        for (int i = 0; i < 4; ++i) {
          int u = tid * 4 + i;
          int row = u >> 3, g8 = (u & 7) * 8;
          stage_cvt8(Wout + (size_t)(v0 + row) * kH + k0 + g8, sWhi, sWlo, row, g8);
        }
        __syncthreads();
        mma64(sXhi, sXlo, sWhi, sWlo, wv, lane, acc);
      }
      // epilogue: bias, store, per-row top-2 over this block's 128 cols
      float bo0 = bout[v0 + wv * 32 + l15];
      float bo1 = bout[v0 + wv * 32 + 16 + l15];
      #pragma unroll
      for (int mt = 0; mt < 4; ++mt) {
        u64 k1[4], k2[4];
        #pragma unroll
        for (int r = 0; r < 4; ++r) {
          float va = acc[mt][0][r] + bo0;
          float vb = acc[mt][1][r] + bo1;
          int b = mt * 16 + l4 * 4 + r;
          unsigned via = v0 + wv * 32 + l15, vib = via + 16;
          size_t ob = ((size_t)b * T + t) * kV;
          out[ob + via] = va;
          out[ob + vib] = vb;
          u64 ka = packKey(va, via), kb = packKey(vb, vib);
          k1[r] = ka > kb ? ka : kb;
          k2[r] = ka > kb ? kb : ka;
        }
        #pragma unroll
        for (int m = 1; m < 16; m <<= 1) {
          #pragma unroll
          for (int r = 0; r < 4; ++r) {
            u64 o1 = __shfl_xor(k1[r], m, 16);
            u64 o2 = __shfl_xor(k2[r], m, 16);
            mergeTop2(k1[r], k2[r], o1, o2);
          }
        }
        if (l15 == 0) {
          #pragma unroll
          for (int r = 0; r < 4; ++r) {
            int b = mt * 16 + l4 * 4 + r;
            sRed[b * 8 + wv * 2 + 0] = k1[r];
            sRed[b * 8 + wv * 2 + 1] = k2[r];
          }
        }
      }
      __syncthreads();
      if (tid < kB) {
        u64 k1 = sRed[tid * 8 + 0], k2 = sRed[tid * 8 + 1];
        #pragma unroll
        for (int w = 1; w < 4; ++w)
          mergeTop2(k1, k2, sRed[tid * 8 + w * 2], sRed[tid * 8 + w * 2 + 1]);
        ws.btop1[(tid << 8) + bid] = k1;
        ws.btop2[(tid << 8) + bid] = k2;
      }
    }
    gbar(ws.bar, bid);

    // ===== F: global argmax + exact rescue -> lastArr[t] =====
    if (bid < kB) {
      const int b = bid;
      u64 k1 = 0ull, k2 = 0ull;
      if (tid < EBLK) {
        k1 = ws.btop1[(b << 8) + tid];
        k2 = ws.btop2[(b << 8) + tid];
      }
      #pragma unroll
      for (int m = 1; m < 64; m <<= 1) {
        u64 o1 = __shfl_xor(k1, m, 64);
        u64 o2 = __shfl_xor(k2, m, 64);
        mergeTop2(k1, k2, o1, o2);
      }
      if ((tid & 63) == 0) { sRed[wv * 2] = k1; sRed[wv * 2 + 1] = k2; }
      __syncthreads();
      if (tid == 0) {
        k1 = sRed[0]; k2 = sRed[1];
        #pragma unroll
        for (int w = 1; w < 4; ++w) mergeTop2(k1, k2, sRed[w * 2], sRed[w * 2 + 1]);
        sFin[0] = k1; sFin[1] = k2;
      }
      __syncthreads();
      k1 = sFin[0]; k2 = sFin[1];
      float v1 = keyVal(k1), v2 = keyVal(k2);
      int i1 = keyIdx(k1), i2 = keyIdx(k2);
      __syncthreads();
      if (v1 - v2 >= GAP_THR) {
        if (tid == 0) ws.lastArr[t * kB + b] = i1;
      } else {
        // exact fp64 recompute of the two candidate logits
        double s1 = 0.0, s2 = 0.0;
        const float* h = ws.h1s + (size_t)b * kH;
        #pragma unroll
        for (int j = 0; j < 4; ++j) {
          int u = tid * 4 + j;
          double x = (double)h[u];
          s1 += x * (double)Wout[(size_t)i1 * kH + u];
          s2 += x * (double)Wout[(size_t)i2 * kH + u];
        }
        double* sD1 = (double*)sRed;
        double* sD2 = sD1 + 256;
        sD1[tid] = s1; sD2[tid] = s2;
        __syncthreads();
        for (int s = 128; s > 0; s >>= 1) {
          if (tid < s) { sD1[tid] += sD1[tid + s]; sD2[tid] += sD2[tid + s]; }
          __syncthreads();
        }
        if (tid == 0) {
          double d1 = sD1[0] + (double)bout[i1];
          double d2 = sD2[0] + (double)bout[i2];
          int win = (d2 > d1 || (d2 == d1 && i2 < i1)) ? i2 : i1;
          ws.lastArr[t * kB + b] = win;
        }
      }
    }
    gbar(ws.bar, bid);
  }
}

extern "C" void kernel_launch(void* const* d_in, const int* in_sizes, int n_in,
                              void* d_out, int out_size, void* d_ws, size_t ws_size,
                              hipStream_t stream) {
  (void)in_sizes; (void)n_in; (void)ws_size;
  const float* hidden = (const float*)d_in[0];
  const float* emb    = (const float*)d_in[1];
  const float* Wih0   = (const float*)d_in[2];
  const float* Whh0   = (const float*)d_in[3];
  const float* bih0   = (const float*)d_in[4];
  const float* bhh0   = (const float*)d_in[5];
  const float* Wih1   = (const float*)d_in[6];
  const float* Whh1   = (const float*)d_in[7];
  const float* bih1   = (const float*)d_in[8];
  const float* bhh1   = (const float*)d_in[9];
  const float* Wout   = (const float*)d_in[10];
  const float* bout   = (const float*)d_in[11];
  float* out = (float*)d_out;

  const int T = out_size / (kB * kV);
  if (T <= 0) return;

  char* w = (char*)d_ws;
  WsPtrs ws;
  ws.P    = (float*)w;    w += (size_t)NKC * kB * kG4 * 4;   // 16 MB
  ws.c0s  = (float*)w;    w += (size_t)kB * kH * 4;
  ws.c1s  = (float*)w;    w += (size_t)kB * kH * 4;
  ws.h1s  = (float*)w;    w += (size_t)kB * kH * 4;
  ws.h0hi = (ushort_t*)w; w += (size_t)kB * kH * 2;
  ws.h0lo = (ushort_t*)w; w += (size_t)kB * kH * 2;
  ws.h1hi = (ushort_t*)w; w += (size_t)kB * kH * 2;
  ws.h1lo = (ushort_t*)w; w += (size_t)kB * kH * 2;
  ws.btop1 = (u64*)w;     w += (size_t)kB * 256 * 8;
  ws.btop2 = (u64*)w;     w += (size_t)kB * 256 * 8;
  ws.lastArr = (int*)w;   w += (size_t)T * kB * 4;
  uintptr_t a = ((uintptr_t)w + 127) & ~(uintptr_t)127;
  ws.bar = (unsigned*)a;

  hipMemsetAsync((void*)ws.bar, 0, 4096, stream);
  hipLaunchKernelGGL(stack_lstm_persistent, dim3(NBLK), dim3(NTHR), 0, stream,
                     hidden, emb, Wih0, Whh0, bih0, bhh0,
                     Wih1, Whh1, bih1, bhh1, Wout, bout,
                     out, T, ws);
}

// Round 4
// 17756.810 us; speedup vs baseline: 1.9671x; 1.0263x over previous
//
#include <hip/hip_runtime.h>
#include <cstdint>
#include <cstddef>

#define DEVINL __device__ __forceinline__

typedef unsigned short ushort_t;
typedef unsigned long long u64;
typedef __attribute__((ext_vector_type(8))) short bf16x8;
typedef __attribute__((ext_vector_type(8))) _Float16 f16x8;
typedef __attribute__((ext_vector_type(4))) float f32x4;

namespace {
constexpr int kB = 64, kH = 1024, kG4 = 4096, kV = 32000;
constexpr int NBLK = 512, NTHR = 512;
constexpr int NKC = 16;          // K-split for gate GEMMs (2048/128)
constexpr int EBLK = 500;        // logits blocks: 500 x 64 vocab cols
constexpr int START_INDEX = 1;
constexpr float GAP_TRIG = 1e-3f;   // trigger fp64 rescue
constexpr float CAND_THR = 2.5e-4f; // candidate inclusion window (>> 6-sigma err ~3e-5)
}

struct WsPtrs {
  float* P;                         // [16][64][4096] gate partials
  float* c0s; float* c1s;           // [64][1024]
  float* h1s;                       // fp32 h1 (rescue)
  ushort_t *h0hi, *h0lo;            // bf16 hi/lo planes
  ushort_t *h1hi, *h1lo;
  ushort_t *h1hi16, *h1lo16;        // fp16 hi/lo planes (for logits)
  u64* btop;                        // [64][500][4] per-block top-4 keys
  int* lastArr;                     // [T][64]
  unsigned* bar;
  ushort_t* img;                    // pre-converted Wout fp16 image (optional)
};

// ---------- numeric helpers ----------
DEVINL ushort_t bf16rne(float f) {
  unsigned u = __float_as_uint(f);
  unsigned r = (u + 0x7FFFu + ((u >> 16) & 1u)) >> 16;
  return (ushort_t)r;
}
DEVINL float bf2f(ushort_t h) { return __uint_as_float(((unsigned)h) << 16); }
DEVINL ushort_t f16bits(_Float16 h) { union { _Float16 h; ushort_t u; } c; c.h = h; return c.u; }

DEVINL void packbf16x8(const float* f, uint4& hi, uint4& lo) {
  unsigned hh[8], ll[8];
  #pragma unroll
  for (int j = 0; j < 8; ++j) {
    ushort_t h = bf16rne(f[j]);
    hh[j] = h;
    ll[j] = bf16rne(f[j] - bf2f(h));
  }
  hi.x = hh[0] | (hh[1] << 16); hi.y = hh[2] | (hh[3] << 16);
  hi.z = hh[4] | (hh[5] << 16); hi.w = hh[6] | (hh[7] << 16);
  lo.x = ll[0] | (ll[1] << 16); lo.y = ll[2] | (ll[3] << 16);
  lo.z = ll[4] | (ll[5] << 16); lo.w = ll[6] | (ll[7] << 16);
}
DEVINL uint4 packf16x8(const float* f) {
  union { ushort_t u[8]; uint4 v; } r;
  #pragma unroll
  for (int j = 0; j < 8; ++j) r.u[j] = f16bits((_Float16)f[j]);
  return r.v;
}

DEVINL u64 packKey(float v, unsigned idx) {
  unsigned u = __float_as_uint(v);
  u = (u & 0x80000000u) ? ~u : (u | 0x80000000u);
  return ((u64)u << 32) | (0xFFFFFFFFu - idx);
}
DEVINL float keyVal(u64 k) {
  unsigned u = (unsigned)(k >> 32);
  u = (u & 0x80000000u) ? (u & 0x7FFFFFFFu) : ~u;
  return __uint_as_float(u);
}
DEVINL int keyIdx(u64 k) { return (int)(0xFFFFFFFFu - (unsigned)(k & 0xFFFFFFFFull)); }

// merge two sorted-desc 4-tuples -> top-4 sorted desc (bitonic, branchless)
DEVINL void topMerge(u64& a0, u64& a1, u64& a2, u64& a3,
                     u64 b0, u64 b1, u64 b2, u64 b3) {
  u64 y0 = a0 > b3 ? a0 : b3;
  u64 y1 = a1 > b2 ? a1 : b2;
  u64 y2 = a2 > b1 ? a2 : b1;
  u64 y3 = a3 > b0 ? a3 : b0;
  u64 t;
  t = y0 > y2 ? y0 : y2; y2 = y0 > y2 ? y2 : y0; y0 = t;
  t = y1 > y3 ? y1 : y3; y3 = y1 > y3 ? y3 : y1; y1 = t;
  t = y0 > y1 ? y0 : y1; y1 = y0 > y1 ? y1 : y0; y0 = t;
  t = y2 > y3 ? y2 : y3; y3 = y2 > y3 ? y3 : y2; y2 = t;
  a0 = y0; a1 = y1; a2 = y2; a3 = y3;
}

// ---------- grid barrier (2-level) ----------
DEVINL void gbar(unsigned* bar, int bid) {
  __syncthreads();
  if (threadIdx.x == 0) {
    __threadfence();
    unsigned g = __hip_atomic_load(bar, __ATOMIC_RELAXED, __HIP_MEMORY_SCOPE_AGENT);
    unsigned* grp = bar + 32 + ((bid >> 4) << 4);
    if (__hip_atomic_fetch_add(grp, 1u, __ATOMIC_ACQ_REL, __HIP_MEMORY_SCOPE_AGENT) == 15u) {
      __hip_atomic_store(grp, 0u, __ATOMIC_RELAXED, __HIP_MEMORY_SCOPE_AGENT);
      if (__hip_atomic_fetch_add(bar + 16, 1u, __ATOMIC_ACQ_REL, __HIP_MEMORY_SCOPE_AGENT) == 31u) {
        __hip_atomic_store(bar + 16, 0u, __ATOMIC_RELAXED, __HIP_MEMORY_SCOPE_AGENT);
        __hip_atomic_store(bar, g + 1u, __ATOMIC_RELEASE, __HIP_MEMORY_SCOPE_AGENT);
      }
    }
    while (__hip_atomic_load(bar, __ATOMIC_RELAXED, __HIP_MEMORY_SCOPE_AGENT) == g) {
      __builtin_amdgcn_s_sleep(2);
    }
    __threadfence();
  }
  __syncthreads();
}

DEVINL f32x4 mfbf(bf16x8 a, bf16x8 b, f32x4 c) {
  return __builtin_amdgcn_mfma_f32_16x16x32_bf16(a, b, c, 0, 0, 0);
}
DEVINL f32x4 mff16(f16x8 a, f16x8 b, f32x4 c) {
  return __builtin_amdgcn_mfma_f32_16x16x32_f16(a, b, c, 0, 0, 0);
}

// ---------- pre-pass: Wout fp32 -> swizzled fp16 image ----------
__global__ __launch_bounds__(256) void wout_prepass(const float* __restrict__ Wout,
                                                    ushort_t* __restrict__ img) {
  int U = blockIdx.x * 256 + threadIdx.x;
  if (U >= EBLK * 16 * 512) return;
  int unit = U & 511, ch = (U >> 9) & 15, vb = U >> 13;
  int row = unit >> 3, j = unit & 7;
  int v = vb * 64 + row;
  int k = ch * 64 + ((j ^ (row & 7)) << 3);
  const float* s = Wout + (size_t)v * kH + k;
  float4 f0 = *(const float4*)s;
  float4 f1 = *(const float4*)(s + 4);
  float ff[8] = {f0.x, f0.y, f0.z, f0.w, f1.x, f1.y, f1.z, f1.w};
  *(uint4*)(img + (size_t)U * 8) = packf16x8(ff);
}

// ---------- gate GEMM phase: block (kc,nt): [64b x 128n] over 128k, bf16x3 ----------
DEVINL void gates_phase(int bid, int tid,
                        const float* __restrict__ Wx, const float* __restrict__ Wh,
                        const float* __restrict__ emb, const int* last_l,
                        const ushort_t* __restrict__ xloHi, const ushort_t* __restrict__ xloLo,
                        const ushort_t* __restrict__ xhiHi, const ushort_t* __restrict__ xhiLo,
                        float* __restrict__ P,
                        ushort_t* sXh, ushort_t* sXl, ushort_t* sWh, ushort_t* sWl) {
  const int kc = bid >> 5, nt = bid & 31;
  const int wv = tid >> 6, lane = tid & 63;
  const int l15 = lane & 15, l4 = lane >> 4;
  const bool lowk = kc < 8;
  f32x4 acc[4];
  #pragma unroll
  for (int mt = 0; mt < 4; ++mt) acc[mt] = (f32x4){0.f, 0.f, 0.f, 0.f};

  const int xrow = tid >> 3, xj = tid & 7;
  const int wrow0 = tid >> 3, wj0 = tid & 7;          // unit tid
  const int wrow1 = (tid + 512) >> 3, wj1 = tid & 7;  // unit tid+512

  #pragma unroll 1
  for (int ch = 0; ch < 2; ++ch) {
    const int kk = kc * 128 + ch * 64;
    const int ksrc = lowk ? kk : kk - kH;
    // ---- issue loads (overlap previous chunk's MFMA) ----
    const int xks = ksrc + ((xj ^ (xrow & 7)) << 3);
    uint4 xvh, xvl; float xf[8];
    const bool xcvt = lowk && (emb != nullptr);
    if (xcvt) {
      const float* s = emb + (size_t)last_l[xrow] * kH + xks;
      float4 a0 = *(const float4*)s; float4 a1 = *(const float4*)(s + 4);
      xf[0]=a0.x; xf[1]=a0.y; xf[2]=a0.z; xf[3]=a0.w;
      xf[4]=a1.x; xf[5]=a1.y; xf[6]=a1.z; xf[7]=a1.w;
    } else {
      const ushort_t* ph = lowk ? xloHi : xhiHi;
      const ushort_t* pl = lowk ? xloLo : xhiLo;
      xvh = *(const uint4*)(ph + (size_t)xrow * kH + xks);
      xvl = *(const uint4*)(pl + (size_t)xrow * kH + xks);
    }
    const float* Wsel = lowk ? Wx : Wh;
    float wf0[8], wf1[8];
    {
      int ks0 = ksrc + ((wj0 ^ (wrow0 & 7)) << 3);
      const float* s = Wsel + (size_t)(nt * 128 + wrow0) * kH + ks0;
      float4 a0 = *(const float4*)s; float4 a1 = *(const float4*)(s + 4);
      wf0[0]=a0.x; wf0[1]=a0.y; wf0[2]=a0.z; wf0[3]=a0.w;
      wf0[4]=a1.x; wf0[5]=a1.y; wf0[6]=a1.z; wf0[7]=a1.w;
      int ks1 = ksrc + ((wj1 ^ (wrow1 & 7)) << 3);
      const float* s2 = Wsel + (size_t)(nt * 128 + wrow1) * kH + ks1;
      float4 b0 = *(const float4*)s2; float4 b1 = *(const float4*)(s2 + 4);
      wf1[0]=b0.x; wf1[1]=b0.y; wf1[2]=b0.z; wf1[3]=b0.w;
      wf1[4]=b1.x; wf1[5]=b1.y; wf1[6]=b1.z; wf1[7]=b1.w;
    }
    __syncthreads();   // previous chunk's LDS reads complete
    // ---- convert + write ----
    if (xcvt) packbf16x8(xf, xvh, xvl);
    *(uint4*)&sXh[tid * 8] = xvh;
    *(uint4*)&sXl[tid * 8] = xvl;
    { uint4 h, l; packbf16x8(wf0, h, l);
      *(uint4*)&sWh[tid * 8] = h; *(uint4*)&sWl[tid * 8] = l; }
    { uint4 h, l; packbf16x8(wf1, h, l);
      *(uint4*)&sWh[(tid + 512) * 8] = h; *(uint4*)&sWl[(tid + 512) * 8] = l; }
    __syncthreads();
    // ---- MFMA ----
    #pragma unroll
    for (int ks = 0; ks < 2; ++ks) {
      bf16x8 ah[4], al[4];
      #pragma unroll
      for (int mt = 0; mt < 4; ++mt) {
        int r = mt * 16 + l15;
        int off = r * 64 + (((ks * 4 + l4) ^ (r & 7)) << 3);
        ah[mt] = *(const bf16x8*)&sXh[off];
        al[mt] = *(const bf16x8*)&sXl[off];
      }
      int rn = wv * 16 + l15;
      int offB = rn * 64 + (((ks * 4 + l4) ^ (rn & 7)) << 3);
      bf16x8 bh = *(const bf16x8*)&sWh[offB];
      bf16x8 bl = *(const bf16x8*)&sWl[offB];
      #pragma unroll
      for (int mt = 0; mt < 4; ++mt) {
        acc[mt] = mfbf(ah[mt], bh, acc[mt]);
        acc[mt] = mfbf(al[mt], bh, acc[mt]);
        acc[mt] = mfbf(ah[mt], bl, acc[mt]);
      }
    }
  }
  // store partials
  const int n = nt * 128 + wv * 16 + l15;
  #pragma unroll
  for (int mt = 0; mt < 4; ++mt)
    #pragma unroll
    for (int r = 0; r < 4; ++r) {
      int b = mt * 16 + l4 * 4 + r;
      P[((size_t)kc * kB + b) * kG4 + n] = acc[mt][r];
    }
}

// ---------- elementwise LSTM cell (deterministic fp64) ----------
DEVINL void elem_phase(int gt, const float* __restrict__ P,
                       const float* __restrict__ bi, const float* __restrict__ bh,
                       float* cs, ushort_t* hhi, ushort_t* hlo,
                       ushort_t* hhi16, ushort_t* hlo16, float* hf32) {
  int b = gt >> 10, u = gt & 1023;
  double g4[4];
  #pragma unroll
  for (int gi = 0; gi < 4; ++gi) {
    int n = gi * kH + u;
    double s = (double)bi[n] + (double)bh[n];
    #pragma unroll 4
    for (int kc = 0; kc < NKC; ++kc)
      s += (double)P[((size_t)kc * kB + b) * kG4 + n];
    g4[gi] = s;
  }
  double c = (double)cs[gt];
  double ig = 1.0 / (1.0 + exp(-g4[0]));
  double fg = 1.0 / (1.0 + exp(-g4[1]));
  double gg = tanh(g4[2]);
  double og = 1.0 / (1.0 + exp(-g4[3]));
  double cn = fg * c + ig * gg;
  double hn = og * tanh(cn);
  cs[gt] = (float)cn;
  float hf = (float)hn;
  ushort_t hb = bf16rne(hf);
  hhi[gt] = hb;
  hlo[gt] = bf16rne(hf - bf2f(hb));
  if (hhi16) {
    _Float16 h16 = (_Float16)hf;
    _Float16 l16 = (_Float16)(hf - (float)h16);
    hhi16[gt] = f16bits(h16);
    hlo16[gt] = f16bits(l16);
    hf32[gt] = hf;
  }
}

__global__ __launch_bounds__(NTHR, 4) void stack_lstm_persistent(
    const float* __restrict__ hidden, const float* __restrict__ emb,
    const float* __restrict__ Wih0, const float* __restrict__ Whh0,
    const float* __restrict__ bih0, const float* __restrict__ bhh0,
    const float* __restrict__ Wih1, const float* __restrict__ Whh1,
    const float* __restrict__ bih1, const float* __restrict__ bhh1,
    const float* __restrict__ Wout, const float* __restrict__ bout,
    float* __restrict__ out, int T, int pre, WsPtrs ws) {
  __shared__ ushort_t sXh[64 * 64], sXl[64 * 64];     // 8KB + 8KB
  __shared__ ushort_t sWh[128 * 64], sWl[128 * 64];   // 16KB + 16KB
  __shared__ u64 sRed[1024];                          // 8KB
  __shared__ int last_l[kB];

  const int tid = threadIdx.x;
  const int bid = blockIdx.x;
  const int wv = tid >> 6, lane = tid & 63;
  const int l15 = lane & 15, l4 = lane >> 4;

  // ---- init state ----
  if (bid < 128) {
    int gt = bid * NTHR + tid;
    float h0f = hidden[gt];
    float h1f = hidden[kB * kH + gt];
    ushort_t a = bf16rne(h0f);
    ws.h0hi[gt] = a; ws.h0lo[gt] = bf16rne(h0f - bf2f(a));
    ushort_t bq = bf16rne(h1f);
    ws.h1hi[gt] = bq; ws.h1lo[gt] = bf16rne(h1f - bf2f(bq));
    _Float16 h16 = (_Float16)h1f;
    _Float16 l16 = (_Float16)(h1f - (float)h16);
    ws.h1hi16[gt] = f16bits(h16);
    ws.h1lo16[gt] = f16bits(l16);
    ws.h1s[gt] = h1f;
    ws.c0s[gt] = 0.f; ws.c1s[gt] = 0.f;
  }
  gbar(ws.bar, bid);

  #pragma unroll 1
  for (int t = 0; t < T; ++t) {
    // ===== A: layer-0 gates -> P =====
    if (tid < kB) last_l[tid] = (t == 0) ? START_INDEX : ws.lastArr[(t - 1) * kB + tid];
    __syncthreads();
    gates_phase(bid, tid, Wih0, Whh0, emb, last_l,
                nullptr, nullptr, ws.h0hi, ws.h0lo,
                ws.P, sXh, sXl, sWh, sWl);
    gbar(ws.bar, bid);

    // ===== B: elem0 ===== (128 blocks x 512 threads = 65536 units exactly)
    if (bid < 128)
      elem_phase(bid * NTHR + tid, ws.P, bih0, bhh0, ws.c0s,
                 ws.h0hi, ws.h0lo, nullptr, nullptr, nullptr);
    gbar(ws.bar, bid);

    // ===== C: layer-1 gates -> P =====
    gates_phase(bid, tid, Wih1, Whh1, nullptr, last_l,
                ws.h0hi, ws.h0lo, ws.h1hi, ws.h1lo,
                ws.P, sXh, sXl, sWh, sWl);
    gbar(ws.bar, bid);

    // ===== D: elem1 =====
    if (bid < 128)
      elem_phase(bid * NTHR + tid, ws.P, bih1, bhh1, ws.c1s,
                 ws.h1hi, ws.h1lo, ws.h1hi16, ws.h1lo16, ws.h1s);
    gbar(ws.bar, bid);

    // ===== E: logits [64b x 64v] per block, fp16 x2 MFMA, top-4 =====
    if (bid < EBLK) {
      const int v0 = bid * 64;
      const int bhalf = wv >> 2, vg = wv & 3;
      f32x4 acc[2];
      acc[0] = (f32x4){0.f, 0.f, 0.f, 0.f};
      acc[1] = (f32x4){0.f, 0.f, 0.f, 0.f};
      ushort_t* wbuf = sWh;   // 64x64 f16
      const int row = tid >> 3, j = tid & 7;

      #pragma unroll 1
      for (int ch = 0; ch < 16; ++ch) {
        const int ks = ch * 64 + ((j ^ (row & 7)) << 3);
        uint4 wreg; float wf[8];
        if (pre) {
          wreg = *(const uint4*)(ws.img + (((size_t)bid * 16 + ch) * 512 + tid) * 8);
        } else {
          const float* s = Wout + (size_t)(v0 + row) * kH + ks;
          float4 a0 = *(const float4*)s; float4 a1 = *(const float4*)(s + 4);
          wf[0]=a0.x; wf[1]=a0.y; wf[2]=a0.z; wf[3]=a0.w;
          wf[4]=a1.x; wf[5]=a1.y; wf[6]=a1.z; wf[7]=a1.w;
        }
        uint4 xh = *(const uint4*)(ws.h1hi16 + (size_t)row * kH + ks);
        uint4 xl = *(const uint4*)(ws.h1lo16 + (size_t)row * kH + ks);
        __syncthreads();
        if (!pre) wreg = packf16x8(wf);
        *(uint4*)&wbuf[tid * 8] = wreg;
        *(uint4*)&sXh[tid * 8] = xh;
        *(uint4*)&sXl[tid * 8] = xl;
        __syncthreads();
        #pragma unroll
        for (int ks2 = 0; ks2 < 2; ++ks2) {
          f16x8 xfh[2], xfl[2];
          #pragma unroll
          for (int mt = 0; mt < 2; ++mt) {
            int r = bhalf * 32 + mt * 16 + l15;
            int off = r * 64 + (((ks2 * 4 + l4) ^ (r & 7)) << 3);
            xfh[mt] = *(const f16x8*)&sXh[off];
            xfl[mt] = *(const f16x8*)&sXl[off];
          }
          int rn = vg * 16 + l15;
          int offB = rn * 64 + (((ks2 * 4 + l4) ^ (rn & 7)) << 3);
          f16x8 wfr = *(const f16x8*)&wbuf[offB];
          #pragma unroll
          for (int mt = 0; mt < 2; ++mt) {
            acc[mt] = mff16(xfh[mt], wfr, acc[mt]);
            acc[mt] = mff16(xfl[mt], wfr, acc[mt]);
          }
        }
      }
      // epilogue: bias, store, per-row top-4
      const unsigned vcol = v0 + vg * 16 + l15;
      float bo = bout[vcol];
      #pragma unroll
      for (int mt = 0; mt < 2; ++mt) {
        #pragma unroll
        for (int r = 0; r < 4; ++r) {
          float val = acc[mt][r] + bo;
          int b = bhalf * 32 + mt * 16 + l4 * 4 + r;
          out[((size_t)b * T + t) * kV + vcol] = val;
          u64 t0 = packKey(val, vcol), t1 = 0, t2 = 0, t3 = 0;
          #pragma unroll
          for (int m = 1; m < 16; m <<= 1) {
            u64 o0 = __shfl_xor(t0, m, 16);
            u64 o1 = __shfl_xor(t1, m, 16);
            u64 o2 = __shfl_xor(t2, m, 16);
            u64 o3 = __shfl_xor(t3, m, 16);
            topMerge(t0, t1, t2, t3, o0, o1, o2, o3);
          }
          if (l15 == 0) {
            u64* d = &sRed[((size_t)b * 4 + vg) * 4];
            d[0] = t0; d[1] = t1; d[2] = t2; d[3] = t3;
          }
        }
      }
      __syncthreads();
      if (tid < kB) {
        const u64* s0 = &sRed[(size_t)tid * 16];
        u64 a0 = s0[0], a1 = s0[1], a2 = s0[2], a3 = s0[3];
        #pragma unroll
        for (int g = 1; g < 4; ++g)
          topMerge(a0, a1, a2, a3, s0[g * 4], s0[g * 4 + 1], s0[g * 4 + 2], s0[g * 4 + 3]);
        u64* d = ws.btop + ((size_t)tid * EBLK + bid) * 4;
        d[0] = a0; d[1] = a1; d[2] = a2; d[3] = a3;
      }
    }
    gbar(ws.bar, bid);

    // ===== F: global top-4 + exact fp64 rescue -> lastArr =====
    if (bid < kB) {
      const int b = bid;
      u64 a0 = 0, a1 = 0, a2 = 0, a3 = 0;
      if (tid < EBLK) {
        const u64* s = ws.btop + ((size_t)b * EBLK + tid) * 4;
        a0 = s[0]; a1 = s[1]; a2 = s[2]; a3 = s[3];
      }
      #pragma unroll
      for (int m = 1; m < 64; m <<= 1) {
        u64 o0 = __shfl_xor(a0, m, 64);
        u64 o1 = __shfl_xor(a1, m, 64);
        u64 o2 = __shfl_xor(a2, m, 64);
        u64 o3 = __shfl_xor(a3, m, 64);
        topMerge(a0, a1, a2, a3, o0, o1, o2, o3);
      }
      if (lane == 0) {
        u64* d = &sRed[wv * 4];
        d[0] = a0; d[1] = a1; d[2] = a2; d[3] = a3;
      }
      __syncthreads();
      if (tid == 0) {
        u64 f0 = sRed[0], f1 = sRed[1], f2 = sRed[2], f3 = sRed[3];
        #pragma unroll
        for (int w = 1; w < 8; ++w)
          topMerge(f0, f1, f2, f3, sRed[w * 4], sRed[w * 4 + 1], sRed[w * 4 + 2], sRed[w * 4 + 3]);
        sRed[520] = f0; sRed[521] = f1; sRed[522] = f2; sRed[523] = f3;
        sRed[524] = (keyVal(f0) - keyVal(f1) < GAP_TRIG) ? 1ull : 0ull;
      }
      __syncthreads();
      u64 f0 = sRed[520], f1 = sRed[521], f2 = sRed[522], f3 = sRed[523];
      bool resc = sRed[524] != 0ull;
      __syncthreads();
      if (!resc) {
        if (tid == 0) ws.lastArr[t * kB + b] = keyIdx(f0);
      } else {
        int cand = tid >> 7, jj = tid & 127;
        int ci;
        if (cand == 0) ci = keyIdx(f0);
        else if (cand == 1) ci = keyIdx(f1);
        else if (cand == 2) ci = keyIdx(f2);
        else ci = keyIdx(f3);
        double s = 0.0;
        const float* h = ws.h1s + (size_t)b * kH;
        const float* wr = Wout + (size_t)ci * kH;
        #pragma unroll
        for (int q = 0; q < 8; ++q) {
          int u = jj * 8 + q;
          s += (double)h[u] * (double)wr[u];
        }
        double* sD = (double*)sRed;   // 4*128 doubles (slots 0..511)
        sD[cand * 128 + jj] = s;
        __syncthreads();
        for (int st = 64; st > 0; st >>= 1) {
          if (jj < st) sD[cand * 128 + jj] += sD[cand * 128 + jj + st];
          __syncthreads();
        }
        if (tid == 0) {
          float v1 = keyVal(f0);
          double d0 = sD[0] + (double)bout[keyIdx(f0)];
          double best = d0; int bi = keyIdx(f0);
          {
            double d = sD[128] + (double)bout[keyIdx(f1)];
            int i = keyIdx(f1);
            if (d > best || (d == best && i < bi)) { best = d; bi = i; }
          }
          if (keyVal(f2) > v1 - CAND_THR) {
            double d = sD[256] + (double)bout[keyIdx(f2)];
            int i = keyIdx(f2);
            if (d > best || (d == best && i < bi)) { best = d; bi = i; }
          }
          if (keyVal(f3) > v1 - CAND_THR) {
            double d = sD[384] + (double)bout[keyIdx(f3)];
            int i = keyIdx(f3);
            if (d > best || (d == best && i < bi)) { best = d; bi = i; }
          }
          ws.lastArr[t * kB + b] = bi;
        }
      }
    }
    gbar(ws.bar, bid);
  }
}

extern "C" void kernel_launch(void* const* d_in, const int* in_sizes, int n_in,
                              void* d_out, int out_size, void* d_ws, size_t ws_size,
                              hipStream_t stream) {
  (void)in_sizes; (void)n_in;
  const float* hidden = (const float*)d_in[0];
  const float* emb    = (const float*)d_in[1];
  const float* Wih0   = (const float*)d_in[2];
  const float* Whh0   = (const float*)d_in[3];
  const float* bih0   = (const float*)d_in[4];
  const float* bhh0   = (const float*)d_in[5];
  const float* Wih1   = (const float*)d_in[6];
  const float* Whh1   = (const float*)d_in[7];
  const float* bih1   = (const float*)d_in[8];
  const float* bhh1   = (const float*)d_in[9];
  const float* Wout   = (const float*)d_in[10];
  const float* bout   = (const float*)d_in[11];
  float* out = (float*)d_out;

  const int T = out_size / (kB * kV);
  if (T <= 0) return;

  char* w = (char*)d_ws;
  WsPtrs ws;
  ws.P      = (float*)w;    w += (size_t)NKC * kB * kG4 * 4;  // 16.78 MB
  ws.c0s    = (float*)w;    w += (size_t)kB * kH * 4;
  ws.c1s    = (float*)w;    w += (size_t)kB * kH * 4;
  ws.h1s    = (float*)w;    w += (size_t)kB * kH * 4;
  ws.h0hi   = (ushort_t*)w; w += (size_t)kB * kH * 2;
  ws.h0lo   = (ushort_t*)w; w += (size_t)kB * kH * 2;
  ws.h1hi   = (ushort_t*)w; w += (size_t)kB * kH * 2;
  ws.h1lo   = (ushort_t*)w; w += (size_t)kB * kH * 2;
  ws.h1hi16 = (ushort_t*)w; w += (size_t)kB * kH * 2;
  ws.h1lo16 = (ushort_t*)w; w += (size_t)kB * kH * 2;
  ws.btop   = (u64*)w;      w += (size_t)kB * EBLK * 4 * 8;   // 1.02 MB
  ws.lastArr = (int*)w;     w += (size_t)T * kB * 4;
  uintptr_t a = ((uintptr_t)w + 127) & ~(uintptr_t)127;
  ws.bar = (unsigned*)a;
  char* after_bar = (char*)a + 4096;

  const size_t imgBytes = (size_t)EBLK * 16 * 512 * 16;       // 65.5 MB
  size_t used = (size_t)(after_bar - (char*)d_ws);
  int pre = (ws_size >= used + imgBytes + (1u << 20)) ? 1 : 0;
  ws.img = (ushort_t*)after_bar;

  hipMemsetAsync((void*)ws.bar, 0, 4096, stream);
  if (pre) {
    int units = EBLK * 16 * 512;
    hipLaunchKernelGGL(wout_prepass, dim3((units + 255) / 256), dim3(256), 0, stream,
                       Wout, ws.img);
  }
  hipLaunchKernelGGL(stack_lstm_persistent, dim3(NBLK), dim3(NTHR), 0, stream,
                     hidden, emb, Wih0, Whh0, bih0, bhh0,
                     Wih1, Whh1, bih1, bhh1, Wout, bout,
                     out, T, pre, ws);
}